// Round 3
// baseline (479.508 us; speedup 1.0000x reference)
//
#include <hip/hip_runtime.h>
#include <hip/hip_bf16.h>
#include <math.h>

// Problem constants
#define BATCH 8
#define CIN 16
#define HID 64
#define S2 1024            // 32*32
#define SP 4096            // 4*32*32 spatial elems per channel
#define CHB 262144         // HID*SP per batch
#define TAU 5
#define GATE_SZ 2097152    // BATCH*CHB floats = one gate buffer
#define EPS 1e-5f

// ws layout (floats): [0..3*GATE_SZ) = u4,u5,u6 ; [3G) Z ; [4G) stats(128 floats).
// Weight packs + PCM live in dead d_out slots (see kernel_launch).
#define WS_Z_OFF   ((size_t)3 * GATE_SZ)
#define WS_ST_OFF  ((size_t)4 * GATE_SZ)
// stats: scores[0..39] (l*8+b)

typedef unsigned short u16;
typedef __attribute__((ext_vector_type(8))) short  short8;
typedef __attribute__((ext_vector_type(8))) u16    ushort8;
typedef __attribute__((ext_vector_type(4))) float  f32x4;

#define N7 (7*27*64*96)
#define NO (27*64*128)
#define N1 (64*128)

__device__ __forceinline__ u16 f2b(float v) {
    __hip_bfloat16 h = __float2bfloat16(v);
    u16 r; __builtin_memcpy(&r, &h, 2); return r;
}

__device__ __forceinline__ float* gate_ptr(float* out, float* ws, int g) {
    return (g < 4) ? (out + (size_t)g * GATE_SZ) : (ws + (size_t)(g - 4) * GATE_SZ);
}

// fast activations: native v_exp_f32 via __expf, clamped so exp never overflows
__device__ __forceinline__ float fsig(float v) {
    v = fminf(fmaxf(v, -30.f), 30.f);
    return 1.f / (1.f + __expf(-v));
}
__device__ __forceinline__ float ftanh(float v) {
    v = fminf(fmaxf(v, -15.f), 15.f);
    const float t = __expf(-2.f * v);
    return (1.f - t) / (1.f + t);
}

// ---- weight pack: A7[g][tap][oc][96], Ao[tap][oc][128], A111[oc][128] (bf16) ----
// Also zeroes the stats block (replaces a hipMemsetAsync dispatch).
__global__ __launch_bounds__(256) void pack_w_k(const float* __restrict__ Wx,
                                                const float* __restrict__ Wh,
                                                const float* __restrict__ w111,
                                                u16* __restrict__ A7, u16* __restrict__ Ao,
                                                u16* __restrict__ A111,
                                                float* __restrict__ stats)
{
    if (blockIdx.x == 0 && threadIdx.x < 128) stats[threadIdx.x] = 0.f;
    const int idx = blockIdx.x * 256 + threadIdx.x;
    if (idx < N7) {
        const int k = idx % 96, oc = (idx / 96) % 64, tap = (idx / (96*64)) % 27, g = idx / (96*64*27);
        float v = 0.f;
        if (k < 16)      v = Wx[((size_t)(g*64 + oc)*16 + k)      * 27 + tap];
        else if (k < 80) v = Wh[((size_t)(g*64 + oc)*64 + (k-16)) * 27 + tap];
        A7[idx] = f2b(v);
    } else if (idx < N7 + NO) {
        const int j = idx - N7;
        const int k = j % 128, oc = (j / 128) % 64, tap = j / (128*64);
        float v = (k < 64) ? Wh[((size_t)(7*64 + oc)*64 + k)      * 27 + tap]
                           : Wh[((size_t)(8*64 + oc)*64 + (k-64)) * 27 + tap];
        Ao[j] = f2b(v);
    } else if (idx < N7 + NO + N1) {
        const int j = idx - N7 - NO;
        A111[j] = f2b(w111[j]);
    }
}

// ---- input pack: XH[b][4096][96], XM[b][4096][96] (bf16, ch-minor) ----
__global__ __launch_bounds__(256) void pack_xhm_k(const float* __restrict__ x,
                                                  const float* __restrict__ h,
                                                  const float* __restrict__ m,
                                                  u16* __restrict__ XH, u16* __restrict__ XM)
{
    __shared__ float t[144][65];
    const int bi = blockIdx.x, b = bi >> 6, s0 = (bi & 63) << 6;
    for (int i = threadIdx.x; i < 144*64; i += 256) {
        const int row = i >> 6, sc = i & 63;
        float v;
        if (row < 16)      v = x[((size_t)b*16 + row)      * SP + s0 + sc];
        else if (row < 80) v = h[((size_t)b*64 + (row-16)) * SP + s0 + sc];
        else               v = m[((size_t)b*64 + (row-80)) * SP + s0 + sc];
        t[row][sc] = v;
    }
    __syncthreads();
    for (int j = threadIdx.x; j < 64*96; j += 256) {
        const int s = j / 96, ch = j % 96;
        const size_t o = ((size_t)b*4096 + s0 + s) * 96 + ch;
        XH[o] = f2b(ch < 80 ? t[ch][s] : 0.f);
        XM[o] = f2b(ch < 16 ? t[ch][s] : (ch < 80 ? t[ch + 64][s] : 0.f));
    }
}

// LDS XOR swizzle: 16B column-block c (0..3) of row r lands at block c^((r>>1)&3).
// Applied identically on staging store and fragment read -> bijective; verified
// round 1: SQ_LDS_BANK_CONFLICT 4.6M -> 0.
__device__ __forceinline__ int swz32(int r, int c) {
    return r * 32 + ((c ^ ((r >> 1) & 3)) << 3);
}

// ---- implicit-GEMM conv via MFMA 16x16x32 bf16 ----
// MODE 0: 7 gate convs (K=96, 27 taps, X = XH or XM per gate, bias bx+bh, write)
// MODE 1: o-gate state conv (K=128, 27 taps, X=PCM, read-add-store into ws u6, NO atomics)
// MODE 2: 1x1x1 conv (K=128, 1 tap, X=PCM, bias b111, write v into ws slot 0)
// (256,4): 4 blocks/CU -> all 896 MODE-0 blocks co-resident (fixes the 58% packing
// of round 0/2 at 3/CU). Register budget at 4 waves/SIMD = 128: acc 64 AGPR +
// SINGLE-buffered frags 32 + addressing ~20 fits; the round-1 spill came from the
// manual double buffer (148 regs). Tripwire: WRITE_SIZE must stay ~57 MB.
// Tap loop: outer kd (runtime 2-3 iters), inner 9 (ky,kx) fully unrolled at
// compile time -> no div/mod VALU, scheduler pipelines loads up to the reg cap.
template<int KCH, int TAPS, int NR, int MODE>
__global__ __launch_bounds__(256, 4) void conv_mfma_k(
    const u16* __restrict__ XA, const u16* __restrict__ XB,
    const u16* __restrict__ Apack,
    const float* __restrict__ bxp, const float* __restrict__ bhp,
    const float* __restrict__ b111,
    float* __restrict__ out, float* __restrict__ ws)
{
    constexpr int YT   = NR + 2;        // y rows in tile (with halo)
    constexpr int ROWS = 4 * YT * 34;   // t * y * x(with halo)
    __shared__ __align__(16) u16 xs[ROWS * 32];

    const int bi = blockIdx.x;
    int g = 0, b, y0, kc_lo = 0, kc_hi = KCH / 32;
    const u16* X; const u16* Ag; float* outp;
    if (MODE == 0) {
        constexpr int YB = 32 / NR;
        g  = bi / (8 * YB);
        b  = (bi / YB) % 8;
        y0 = (bi % YB) * NR;
        X  = (g >= 3 && g <= 5) ? XB : XA;
        Ag = Apack + (size_t)g * TAPS * 64 * KCH;
        outp = gate_ptr(out, ws, g) + (size_t)b * CHB;
    } else if (MODE == 1) {
        b = bi >> 5; y0 = bi & 31;
        X = XA; Ag = Apack;
        outp = ws + (size_t)2 * GATE_SZ + (size_t)b * CHB;
    } else {
        b = bi >> 5; y0 = bi & 31;
        X = XA; Ag = Apack;
        outp = ws + (size_t)b * CHB;
    }
    const u16* Xb = X + (size_t)b * 4096 * KCH;

    const int tid  = threadIdx.x;
    const int w    = tid >> 6;          // wave = output t-plane
    const int lane = tid & 63;
    const int xn   = lane & 15, quad = lane >> 4;

    f32x4 acc[4][2 * NR] = {};

    for (int kc = kc_lo; kc < kc_hi; ++kc) {
        if (kc != kc_lo) __syncthreads();
        // stage 32-channel slab of the (t, y-halo, x-halo) tile into LDS (swizzled)
        for (int cix = tid; cix < ROWS * 4; cix += 256) {
            const int r = cix >> 2, sub = cix & 3;
            const int t = r / (YT * 34), rem = r % (YT * 34);
            const int yy = rem / 34, xx = rem % 34;
            const int gy = y0 + yy - 1, gx = xx - 1;
            ushort8 v = {0, 0, 0, 0, 0, 0, 0, 0};
            if ((unsigned)gy < 32u && (unsigned)gx < 32u)
                v = *(const ushort8*)&Xb[(size_t)(t * 1024 + gy * 32 + gx) * KCH + kc * 32 + sub * 8];
            *(ushort8*)&xs[swz32(r, sub)] = v;
        }
        __syncthreads();

        if (TAPS == 27) {
            // valid kd range per wave (t-plane); inner 9 taps compile-time
            const int kd_lo = (w == 0) ? 1 : 0;
            const int kd_hi = (w == 3) ? 2 : 3;
            for (int kd = kd_lo; kd < kd_hi; ++kd) {
                const int tin  = w + kd - 1;
                const int rowt = tin * YT * 34;
                #pragma unroll
                for (int jj = 0; jj < 9; ++jj) {
                    const int ky = jj / 3, kx = jj % 3;     // compile-time
                    short8 a[4], bf[2 * NR];
                    #pragma unroll
                    for (int mt = 0; mt < 4; ++mt)
                        a[mt] = *(const short8*)
                            &Ag[(size_t)((kd * 9 + jj) * 64 + mt * 16 + xn) * KCH + kc * 32 + quad * 8];
                    #pragma unroll
                    for (int nt = 0; nt < 2 * NR; ++nt) {
                        const int ysub = nt >> 1, xh = nt & 1;
                        const int row = rowt + (ysub + ky) * 34 + xh * 16 + xn + kx;
                        bf[nt] = *(const short8*)&xs[swz32(row, quad)];
                    }
                    #pragma unroll
                    for (int nt = 0; nt < 2 * NR; ++nt)
                        #pragma unroll
                        for (int mt = 0; mt < 4; ++mt)
                            acc[mt][nt] = __builtin_amdgcn_mfma_f32_16x16x32_bf16(a[mt], bf[nt], acc[mt][nt], 0, 0, 0);
                }
            }
        } else {
            // single center tap (kd=ky=kx=1)
            short8 a[4], bf[2 * NR];
            #pragma unroll
            for (int mt = 0; mt < 4; ++mt)
                a[mt] = *(const short8*)&Ag[(size_t)(mt * 16 + xn) * KCH + kc * 32 + quad * 8];
            #pragma unroll
            for (int nt = 0; nt < 2 * NR; ++nt) {
                const int ysub = nt >> 1, xh = nt & 1;
                const int row = (w * YT + ysub + 1) * 34 + xh * 16 + xn + 1;
                bf[nt] = *(const short8*)&xs[swz32(row, quad)];
            }
            #pragma unroll
            for (int nt = 0; nt < 2 * NR; ++nt)
                #pragma unroll
                for (int mt = 0; mt < 4; ++mt)
                    acc[mt][nt] = __builtin_amdgcn_mfma_f32_16x16x32_bf16(a[mt], bf[nt], acc[mt][nt], 0, 0, 0);
        }
    }

    // epilogue: C/D layout col=lane&15, row=quad*4+reg
    #pragma unroll
    for (int mt = 0; mt < 4; ++mt)
    #pragma unroll
    for (int nt = 0; nt < 2 * NR; ++nt) {
        const int ysub = nt >> 1, xh = nt & 1;
        const int sp = w * 1024 + (y0 + ysub) * 32 + xh * 16 + xn;
        #pragma unroll
        for (int reg = 0; reg < 4; ++reg) {
            const int oc = mt * 16 + quad * 4 + reg;
            float bias;
            if (MODE == 0)      bias = bxp[g * 64 + oc] + bhp[g * 64 + oc];
            else if (MODE == 1) bias = bhp[7 * 64 + oc] + bhp[8 * 64 + oc];
            else                bias = b111[oc];
            float* p = outp + (size_t)oc * SP + sp;
            float vv = acc[mt][nt][reg] + bias;
            if (MODE == 1) vv += *p;     // accumulate onto MODE-0 g6 output; each
            *p = vv;                     // element owned by exactly one block
        }
    }
}

// ---- LN3 stats only (gates 0..5): mu/rstd per (g,b,c) -> lnstats table ----
// Activation+normalization is applied on-the-fly by consumers (scores_k, cm_pcm_k),
// eliding the 48 MB activated-gate write pass.
__global__ __launch_bounds__(256) void ln3_stats_k(float* __restrict__ out,
                                                   float* __restrict__ ws,
                                                   float* __restrict__ lnstats)
{
    const int blk = blockIdx.x;                 // g*512 + b*64 + chn
    const int g = blk >> 9;
    const float* p = gate_ptr(out, ws, g) + (size_t)(blk & 511) * SP;
    const int tid = threadIdx.x;

    float s = 0.f, s2 = 0.f;
    for (int k = tid; k < SP; k += 256) { float v = p[k]; s += v; s2 += v * v; }
    #pragma unroll
    for (int off = 32; off > 0; off >>= 1) { s += __shfl_down(s, off); s2 += __shfl_down(s2, off); }
    __shared__ float rs[4], rs2[4];
    if ((tid & 63) == 0) { rs[tid >> 6] = s; rs2[tid >> 6] = s2; }
    __syncthreads();
    if (tid == 0) {
        float S  = rs[0] + rs[1] + rs[2] + rs[3];
        float Sq = rs2[0] + rs2[1] + rs2[2] + rs2[3];
        float mu  = S * (1.f / SP);
        float var = Sq * (1.f / SP) - mu * mu;
        lnstats[2 * blk]     = mu;
        lnstats[2 * blk + 1] = rsqrtf(var + EPS);
    }
}

// ---- LayerNorm + activation in place (gate 6 / o-gate only) ----
__global__ __launch_bounds__(256) void ln3_act_k(float* __restrict__ out,
                                                 float* __restrict__ ws, int gate0)
{
    const int blk = blockIdx.x;
    const int g = gate0 + (blk >> 9);
    float* p = gate_ptr(out, ws, g) + (size_t)(blk & 511) * SP;
    const int tid = threadIdx.x;

    float s = 0.f, s2 = 0.f;
    for (int k = tid; k < SP; k += 256) { float v = p[k]; s += v; s2 += v * v; }
    #pragma unroll
    for (int off = 32; off > 0; off >>= 1) { s += __shfl_down(s, off); s2 += __shfl_down(s2, off); }
    __shared__ float rs[4], rs2[4], stat[2];
    if ((tid & 63) == 0) { rs[tid >> 6] = s; rs2[tid >> 6] = s2; }
    __syncthreads();
    if (tid == 0) {
        float S  = rs[0] + rs[1] + rs[2] + rs[3];
        float Sq = rs2[0] + rs2[1] + rs2[2] + rs2[3];
        float mu  = S * (1.f / SP);
        float var = Sq * (1.f / SP) - mu * mu;
        stat[0] = mu; stat[1] = rsqrtf(var + EPS);
    }
    __syncthreads();
    const float mu = stat[0], r = stat[1];
    for (int k = tid; k < SP; k += 256)
        p[k] = fsig((p[k] - mu) * r);           // gate 6 is sigmoid
}

// ---- attention scores: sigma(LN(u0)) applied on the fly; one r-read, 5 dots ----
__global__ __launch_bounds__(256) void scores_k(const float* __restrict__ u0,
                                                const float* __restrict__ chist,
                                                const float* __restrict__ lnstats,
                                                float* __restrict__ stats)
{
    const int blk = blockIdx.x;            // 512 = 8 b * 64 chn (chunk == channel)
    const int b = blk >> 6, chn = blk & 63;
    const float mu = lnstats[2 * (b * 64 + chn)];
    const float rr = lnstats[2 * (b * 64 + chn) + 1];
    const float* rp = u0 + (size_t)b * CHB;
    const int lo = chn * SP;
    float s[TAU] = {};
    for (int k = lo + threadIdx.x; k < lo + SP; k += 256) {
        const float rv = fsig((rp[k] - mu) * rr);
        #pragma unroll
        for (int l = 0; l < TAU; ++l) s[l] += rv * chist[(size_t)(l * BATCH + b) * CHB + k];
    }
    __shared__ float rsh[TAU][4];
    #pragma unroll
    for (int l = 0; l < TAU; ++l) {
        float v = s[l];
        #pragma unroll
        for (int off = 32; off > 0; off >>= 1) v += __shfl_down(v, off);
        if ((threadIdx.x & 63) == 0) rsh[l][threadIdx.x >> 6] = v;
    }
    __syncthreads();
    if (threadIdx.x < TAU) {
        const int l = threadIdx.x;
        atomicAdd(&stats[l * 8 + b],
                  (rsh[l][0] + rsh[l][1] + rsh[l][2] + rsh[l][3]) * (1.f / 64.f));
    }
}

// ---- z = chist[4,b] + sum_l attn[b,l]*chist[l,b]; softmax fused; per-block partials ----
__global__ __launch_bounds__(256) void recall_k(const float* __restrict__ chist,
                                                float* __restrict__ ws,
                                                float* __restrict__ part)
{
    const float* stats = ws + WS_ST_OFF;
    const int blk = blockIdx.x;
    const int b = blk >> 10;
    const int idx = (blk & 1023) * 256 + threadIdx.x;

    // softmax over dim 0 (batch) of scores[l*8+b], per l — 5 threads, broadcast via LDS
    __shared__ float attn[TAU];
    if (threadIdx.x < TAU) {
        const int l = threadIdx.x;
        float mx = -1e30f;
        for (int bb = 0; bb < BATCH; ++bb) mx = fmaxf(mx, stats[l * 8 + bb]);
        float sum = 0.f, e = 0.f;
        for (int bb = 0; bb < BATCH; ++bb) {
            float t = __expf(stats[l * 8 + bb] - mx);
            sum += t;
            if (bb == b) e = t;
        }
        attn[l] = e / sum;
    }
    __syncthreads();
    const float a0 = attn[0], a1 = attn[1], a2 = attn[2], a3 = attn[3], a4 = attn[4];

    const size_t e = (size_t)b * CHB + idx;
    const size_t LB = (size_t)BATCH * CHB;
    float z = chist[4 * LB + e] * (1.f + a4)
            + a0 * chist[0 * LB + e] + a1 * chist[1 * LB + e]
            + a2 * chist[2 * LB + e] + a3 * chist[3 * LB + e];
    ws[WS_Z_OFF + e] = z;

    float s = z, s2 = z * z;
    #pragma unroll
    for (int off = 32; off > 0; off >>= 1) { s += __shfl_down(s, off); s2 += __shfl_down(s2, off); }
    __shared__ float rs[4], rs2[4];
    if ((threadIdx.x & 63) == 0) { rs[threadIdx.x >> 6] = s; rs2[threadIdx.x >> 6] = s2; }
    __syncthreads();
    if (threadIdx.x == 0) {
        part[blk]        = rs[0] + rs[1] + rs[2] + rs[3];
        part[8192 + blk] = rs2[0] + rs2[1] + rs2[2] + rs2[3];
    }
}

// ---- fused: LN4 stats + LN3+act of gates 1..5 on the fly + c,m_new + PCM pack ----
__global__ __launch_bounds__(256) void cm_pcm_k(float* __restrict__ out, float* __restrict__ ws,
                                                const float* __restrict__ m,
                                                const float* __restrict__ lnw,
                                                const float* __restrict__ lnb,
                                                const float* __restrict__ part,
                                                const float* __restrict__ lnstats,
                                                u16* __restrict__ PCM)
{
    __shared__ __align__(16) u16 tl[64][136];   // [sp][128 ch + pad], 16B-aligned rows
    __shared__ float lst[5][64][2];             // LN3 stats for gates 1..5, this batch
    const int bi = blockIdx.x;
    const int b = bi >> 6;
    const int s0 = (bi & 63) << 6;

    // stage LN3 stats (gates 1..5) + re-reduce the 1024 LN4 partials for this batch
    for (int j = threadIdx.x; j < 5 * 64; j += 256) {
        const int gg = j >> 6, chn = j & 63;
        lst[gg][chn][0] = lnstats[2 * ((gg + 1) * 512 + b * 64 + chn)];
        lst[gg][chn][1] = lnstats[2 * ((gg + 1) * 512 + b * 64 + chn) + 1];
    }
    float s = 0.f, s2 = 0.f;
    for (int j = threadIdx.x; j < 1024; j += 256) {
        s  += part[b * 1024 + j];
        s2 += part[8192 + b * 1024 + j];
    }
    #pragma unroll
    for (int off = 32; off > 0; off >>= 1) { s += __shfl_down(s, off); s2 += __shfl_down(s2, off); }
    __shared__ float rs[4], rs2[4], st[2];
    if ((threadIdx.x & 63) == 0) { rs[threadIdx.x >> 6] = s; rs2[threadIdx.x >> 6] = s2; }
    __syncthreads();
    if (threadIdx.x == 0) {
        float S  = rs[0] + rs[1] + rs[2] + rs[3];
        float Sq = rs2[0] + rs2[1] + rs2[2] + rs2[3];
        float mu  = S * (1.f / CHB);
        float var = Sq * (1.f / CHB) - mu * mu;
        st[0] = mu; st[1] = rsqrtf(var + EPS);
    }
    __syncthreads();
    const float mu = st[0], rstd = st[1];

    for (int i = threadIdx.x; i < 1024; i += 256) {       // 64ch x 16 float4
        const int chn = i >> 4;
        const int sp4 = (i & 15) << 2;
        const size_t e = (size_t)b * CHB + (size_t)chn * SP + s0 + sp4;
        const size_t le = (size_t)chn * SP + s0 + sp4;
        float4 z  = *(const float4*)&ws[WS_Z_OFF + e];
        float4 u1 = *(const float4*)&gate_ptr(out, ws, 1)[e];
        float4 u2 = *(const float4*)&gate_ptr(out, ws, 2)[e];
        float4 u3 = *(const float4*)&gate_ptr(out, ws, 3)[e];
        float4 u4 = *(const float4*)&gate_ptr(out, ws, 4)[e];
        float4 u5 = *(const float4*)&gate_ptr(out, ws, 5)[e];
        float4 mm = *(const float4*)&m[e];
        float4 lw = *(const float4*)&lnw[le];
        float4 lb = *(const float4*)&lnb[le];
        const float m1 = lst[0][chn][0], r1 = lst[0][chn][1];
        const float m2 = lst[1][chn][0], r2 = lst[1][chn][1];
        const float m3 = lst[2][chn][0], r3 = lst[2][chn][1];
        const float m4 = lst[3][chn][0], r4 = lst[3][chn][1];
        const float m5 = lst[4][chn][0], r5 = lst[4][chn][1];
        float4 c, mn;
        {
            const float uu1[4] = {u1.x, u1.y, u1.z, u1.w};
            const float uu2[4] = {u2.x, u2.y, u2.z, u2.w};
            const float uu3[4] = {u3.x, u3.y, u3.z, u3.w};
            const float uu4[4] = {u4.x, u4.y, u4.z, u4.w};
            const float uu5[4] = {u5.x, u5.y, u5.z, u5.w};
            const float zz[4]  = {z.x, z.y, z.z, z.w};
            const float mmv[4] = {mm.x, mm.y, mm.z, mm.w};
            const float lwv[4] = {lw.x, lw.y, lw.z, lw.w};
            const float lbv[4] = {lb.x, lb.y, lb.z, lb.w};
            float cv[4], mv[4];
            #pragma unroll
            for (int k = 0; k < 4; ++k) {
                const float gi = fsig ((uu1[k] - m1) * r1);
                const float gg = ftanh((uu2[k] - m2) * r2);
                const float ip = fsig ((uu3[k] - m3) * r3);
                const float gp = ftanh((uu4[k] - m4) * r4);
                const float fp = fsig ((uu5[k] - m5) * r5);
                cv[k] = gi * gg + (zz[k] - mu) * rstd * lwv[k] + lbv[k];
                mv[k] = ip * gp + fp * mmv[k];
                tl[sp4 + k][chn]      = f2b(cv[k]);
                tl[sp4 + k][64 + chn] = f2b(mv[k]);
            }
            c.x = cv[0]; c.y = cv[1]; c.z = cv[2]; c.w = cv[3];
            mn.x = mv[0]; mn.y = mv[1]; mn.z = mv[2]; mn.w = mv[3];
        }
        *(float4*)&out[(size_t)4 * GATE_SZ + e] = c;
        *(float4*)&out[(size_t)5 * GATE_SZ + e] = mn;
    }
    __syncthreads();
    for (int j = threadIdx.x; j < 1024; j += 256) {       // 64 s x 16 ushort8
        const int sidx = j >> 4, c8 = (j & 15) << 3;
        ushort8 v = *(const ushort8*)&tl[sidx][c8];
        *(ushort8*)&PCM[((size_t)b * 4096 + s0 + sidx) * 128 + c8] = v;
    }
}

// ---- merged tail: c_history_new[0:4] = c_history[1:5]  AND  h_new = o * tanh(v) ----
__global__ __launch_bounds__(256) void tail_k(const float* __restrict__ chist,
                                              const float* __restrict__ o,
                                              const float* __restrict__ v,
                                              float* __restrict__ out)
{
    const int bi = blockIdx.x;
    if (bi < 8192) {
        const size_t i = (size_t)bi * 256 + threadIdx.x;
        ((float4*)out)[i] = ((const float4*)(chist + GATE_SZ))[i];
    } else {
        const size_t i = (size_t)(bi - 8192) * 256 + threadIdx.x;
        float4 ov = ((const float4*)o)[i], vv = ((const float4*)v)[i];
        float4 r;
        r.x = ov.x * ftanh(vv.x); r.y = ov.y * ftanh(vv.y);
        r.z = ov.z * ftanh(vv.z); r.w = ov.w * ftanh(vv.w);
        ((float4*)(out + (size_t)6 * GATE_SZ))[i] = r;
    }
}

extern "C" void kernel_launch(void* const* d_in, const int* in_sizes, int n_in,
                              void* d_out, int out_size, void* d_ws, size_t ws_size,
                              hipStream_t stream)
{
    const float* x    = (const float*)d_in[0];
    const float* ch   = (const float*)d_in[1];
    const float* m    = (const float*)d_in[2];
    const float* h    = (const float*)d_in[3];
    const float* Wx   = (const float*)d_in[4];
    const float* bx   = (const float*)d_in[5];
    const float* Wh   = (const float*)d_in[6];
    const float* bh   = (const float*)d_in[7];
    const float* w111 = (const float*)d_in[8];
    const float* b111 = (const float*)d_in[9];
    const float* lnw  = (const float*)d_in[10];
    const float* lnb  = (const float*)d_in[11];
    float* out = (float*)d_out;
    float* ws  = (float*)d_ws;

    // Scratch placement in DEAD d_out slots (ws stays within the proven
    // 4*GATE_SZ+128-float footprint):
    //   slot 0: u0 (raw r) until scores_k; then PCM (8 MB) written by cm_pcm_k,
    //           read by conv MODE 1/2, finally overwritten by tail_k (hist copy).
    //   slot 4: XH (6 MB) dead after MODE 0; slot rewritten by cm_pcm_k with c.
    //   slot 5: A7 (2.2 MB) dead after MODE 0; rewritten by cm_pcm_k (m_new).
    //   slot 6: XM (6 MB) + Ao/A111 (0.46 MB) + LN4 partials (64 KB) + LN3 stats
    //           (24 KB) — all dead before tail_k writes h_new at the very end.
    u16* XH   = (u16*)(out + (size_t)4 * GATE_SZ);
    u16* A7   = (u16*)(out + (size_t)5 * GATE_SZ);
    u16* XM   = (u16*)(out + (size_t)6 * GATE_SZ);
    u16* Ao   = XM + (size_t)BATCH * 4096 * 96;      // behind XM, same slot
    u16* A111 = Ao + (size_t)NO;
    u16* PCM  = (u16*)out;                           // slot 0 (dead after scores_k)
    float* part    = (float*)(A111 + N1);            // 16384 floats, slot-6 dead zone
    float* lnstats = part + 16384;                   // 6144 floats, slot-6 dead zone
    float* stats   = ws + WS_ST_OFF;

    pack_w_k<<<(N7 + NO + N1 + 255) / 256, 256, 0, stream>>>(Wx, Wh, w111, A7, Ao, A111, stats);
    pack_xhm_k<<<512, 256, 0, stream>>>(x, h, m, XH, XM);

    conv_mfma_k<96, 27, 2, 0><<<896, 256, 0, stream>>>(XH, XM, A7, bx, bh, nullptr, out, ws);
    ln3_stats_k<<<3072, 256, 0, stream>>>(out, ws, lnstats);         // gates 0..5 stats only

    scores_k<<<512, 256, 0, stream>>>(out, ch, lnstats, stats);      // sigma(LN(u0)) inline
    recall_k<<<8192, 256, 0, stream>>>(ch, ws, part);                // softmax fused
    cm_pcm_k<<<512, 256, 0, stream>>>(out, ws, m, lnw, lnb, part, lnstats, PCM);

    conv_mfma_k<128, 27, 1, 1><<<256, 256, 0, stream>>>(PCM, nullptr, Ao, nullptr, bh, nullptr, out, ws);
    ln3_act_k<<<512, 256, 0, stream>>>(out, ws, 6);                  // gate 6 (o)
    conv_mfma_k<128, 1, 1, 2><<<256, 256, 0, stream>>>(PCM, nullptr, A111, nullptr, nullptr, b111, out, ws);

    tail_k<<<10240, 256, 0, stream>>>(ch, ws + (size_t)2 * GATE_SZ, ws, out);
}

// Round 4
// 392.131 us; speedup vs baseline: 1.2228x; 1.2228x over previous
//
#include <hip/hip_runtime.h>
#include <hip/hip_bf16.h>
#include <math.h>

// Problem constants
#define BATCH 8
#define CIN 16
#define HID 64
#define S2 1024            // 32*32
#define SP 4096            // 4*32*32 spatial elems per channel
#define CHB 262144         // HID*SP per batch
#define TAU 5
#define GATE_SZ 2097152    // BATCH*CHB floats = one gate buffer
#define EPS 1e-5f

// ws layout (floats): [0..3*GATE_SZ) = u4,u5,u6 ; [3G) Z ; [4G) stats(128 floats).
// Weight packs + PCM live in dead d_out slots (see kernel_launch).
#define WS_Z_OFF   ((size_t)3 * GATE_SZ)
#define WS_ST_OFF  ((size_t)4 * GATE_SZ)
// stats: scores[0..39] (l*8+b)

typedef unsigned short u16;
typedef __attribute__((ext_vector_type(8))) short  short8;
typedef __attribute__((ext_vector_type(8))) u16    ushort8;
typedef __attribute__((ext_vector_type(4))) float  f32x4;

#define N7 (7*27*64*96)
#define NO (27*64*128)
#define N1 (64*128)

__device__ __forceinline__ u16 f2b(float v) {
    __hip_bfloat16 h = __float2bfloat16(v);
    u16 r; __builtin_memcpy(&r, &h, 2); return r;
}

__device__ __forceinline__ float* gate_ptr(float* out, float* ws, int g) {
    return (g < 4) ? (out + (size_t)g * GATE_SZ) : (ws + (size_t)(g - 4) * GATE_SZ);
}

// fast activations: native v_exp_f32 via __expf, clamped so exp never overflows
__device__ __forceinline__ float fsig(float v) {
    v = fminf(fmaxf(v, -30.f), 30.f);
    return 1.f / (1.f + __expf(-v));
}
__device__ __forceinline__ float ftanh(float v) {
    v = fminf(fmaxf(v, -15.f), 15.f);
    const float t = __expf(-2.f * v);
    return (1.f - t) / (1.f + t);
}

// ---- weight pack: A7[g][tap][oc][96], Ao[tap][oc][128], A111[oc][128] (bf16) ----
// Also zeroes the stats block (replaces a hipMemsetAsync dispatch).
__global__ __launch_bounds__(256) void pack_w_k(const float* __restrict__ Wx,
                                                const float* __restrict__ Wh,
                                                const float* __restrict__ w111,
                                                u16* __restrict__ A7, u16* __restrict__ Ao,
                                                u16* __restrict__ A111,
                                                float* __restrict__ stats)
{
    if (blockIdx.x == 0 && threadIdx.x < 128) stats[threadIdx.x] = 0.f;
    const int idx = blockIdx.x * 256 + threadIdx.x;
    if (idx < N7) {
        const int k = idx % 96, oc = (idx / 96) % 64, tap = (idx / (96*64)) % 27, g = idx / (96*64*27);
        float v = 0.f;
        if (k < 16)      v = Wx[((size_t)(g*64 + oc)*16 + k)      * 27 + tap];
        else if (k < 80) v = Wh[((size_t)(g*64 + oc)*64 + (k-16)) * 27 + tap];
        A7[idx] = f2b(v);
    } else if (idx < N7 + NO) {
        const int j = idx - N7;
        const int k = j % 128, oc = (j / 128) % 64, tap = j / (128*64);
        float v = (k < 64) ? Wh[((size_t)(7*64 + oc)*64 + k)      * 27 + tap]
                           : Wh[((size_t)(8*64 + oc)*64 + (k-64)) * 27 + tap];
        Ao[j] = f2b(v);
    } else if (idx < N7 + NO + N1) {
        const int j = idx - N7 - NO;
        A111[j] = f2b(w111[j]);
    }
}

// ---- input pack: XH[b][4096][96], XM[b][4096][96] (bf16, ch-minor) ----
__global__ __launch_bounds__(256) void pack_xhm_k(const float* __restrict__ x,
                                                  const float* __restrict__ h,
                                                  const float* __restrict__ m,
                                                  u16* __restrict__ XH, u16* __restrict__ XM)
{
    __shared__ float t[144][65];
    const int bi = blockIdx.x, b = bi >> 6, s0 = (bi & 63) << 6;
    for (int i = threadIdx.x; i < 144*64; i += 256) {
        const int row = i >> 6, sc = i & 63;
        float v;
        if (row < 16)      v = x[((size_t)b*16 + row)      * SP + s0 + sc];
        else if (row < 80) v = h[((size_t)b*64 + (row-16)) * SP + s0 + sc];
        else               v = m[((size_t)b*64 + (row-80)) * SP + s0 + sc];
        t[row][sc] = v;
    }
    __syncthreads();
    for (int j = threadIdx.x; j < 64*96; j += 256) {
        const int s = j / 96, ch = j % 96;
        const size_t o = ((size_t)b*4096 + s0 + s) * 96 + ch;
        XH[o] = f2b(ch < 80 ? t[ch][s] : 0.f);
        XM[o] = f2b(ch < 16 ? t[ch][s] : (ch < 80 ? t[ch + 64][s] : 0.f));
    }
}

// LDS XOR swizzle: 16B column-block c (0..3) of row r lands at block c^((r>>1)&3).
// Applied identically on staging store and fragment read -> bijective; verified
// round 1: SQ_LDS_BANK_CONFLICT 4.6M -> 0.
__device__ __forceinline__ int swz32(int r, int c) {
    return r * 32 + ((c ^ ((r >> 1) & 3)) << 3);
}

// ---- implicit-GEMM conv via MFMA 16x16x32 bf16 ----
// MODE 0: 7 gate convs (K=96, 27 taps, X = XH or XM per gate, bias bx+bh, write)
//         OC-SPLIT: each block computes 32 of the 64 output channels (MT=2 m-tiles)
//         -> acc 32 regs + a 16 + bf 32 ~= 105 total, fits the 128-reg budget at
//         4 blocks/CU (MINW=4). Grid 1792 at 1024 slots = 87.5% packing (vs 58%).
//         Round-1/3 lesson: 64-reg acc at MINW=4 spills (FETCH 38->344 MB).
//         Tripwire: WRITE_SIZE must stay ~57 MB, FETCH ~40 MB.
// MODE 1: o-gate state conv (K=128, 27 taps, X=PCM, read-add-store, NO atomics), MINW=3
// MODE 2: 1x1x1 conv (K=128, 1 tap, X=PCM, bias b111, write into ws slot 0), MINW=3
template<int KCH, int TAPS, int NR, int MODE, int MT, int MINW>
__global__ __launch_bounds__(256, MINW) void conv_mfma_k(
    const u16* __restrict__ XA, const u16* __restrict__ XB,
    const u16* __restrict__ Apack,
    const float* __restrict__ bxp, const float* __restrict__ bhp,
    const float* __restrict__ b111,
    float* __restrict__ out, float* __restrict__ ws)
{
    constexpr int YT   = NR + 2;        // y rows in tile (with halo)
    constexpr int ROWS = 4 * YT * 34;   // t * y * x(with halo)
    __shared__ __align__(16) u16 xs[ROWS * 32];

    const int bi = blockIdx.x;
    int g = 0, b, y0, ocb = 0, kc_lo = 0, kc_hi = KCH / 32;
    const u16* X; const u16* Ag; float* outp;
    if (MODE == 0) {
        constexpr int YB = 32 / NR;
        ocb = (bi & 1) * 32;            // oc half
        const int r2 = bi >> 1;
        g  = r2 / (8 * YB);
        b  = (r2 / YB) % 8;
        y0 = (r2 % YB) * NR;
        X  = (g >= 3 && g <= 5) ? XB : XA;
        Ag = Apack + (size_t)g * TAPS * 64 * KCH;
        outp = gate_ptr(out, ws, g) + (size_t)b * CHB;
    } else if (MODE == 1) {
        b = bi >> 5; y0 = bi & 31;
        X = XA; Ag = Apack;
        outp = ws + (size_t)2 * GATE_SZ + (size_t)b * CHB;
    } else {
        b = bi >> 5; y0 = bi & 31;
        X = XA; Ag = Apack;
        outp = ws + (size_t)b * CHB;
    }
    const u16* Xb = X + (size_t)b * 4096 * KCH;

    const int tid  = threadIdx.x;
    const int w    = tid >> 6;          // wave = output t-plane
    const int lane = tid & 63;
    const int xn   = lane & 15, quad = lane >> 4;

    f32x4 acc[MT][2 * NR] = {};

    for (int kc = kc_lo; kc < kc_hi; ++kc) {
        if (kc != kc_lo) __syncthreads();
        // stage 32-channel slab of the (t, y-halo, x-halo) tile into LDS (swizzled)
        for (int cix = tid; cix < ROWS * 4; cix += 256) {
            const int r = cix >> 2, sub = cix & 3;
            const int t = r / (YT * 34), rem = r % (YT * 34);
            const int yy = rem / 34, xx = rem % 34;
            const int gy = y0 + yy - 1, gx = xx - 1;
            ushort8 v = {0, 0, 0, 0, 0, 0, 0, 0};
            if ((unsigned)gy < 32u && (unsigned)gx < 32u)
                v = *(const ushort8*)&Xb[(size_t)(t * 1024 + gy * 32 + gx) * KCH + kc * 32 + sub * 8];
            *(ushort8*)&xs[swz32(r, sub)] = v;
        }
        __syncthreads();

        if (TAPS == 27) {
            // valid kd range per wave (t-plane); inner 9 taps compile-time
            const int kd_lo = (w == 0) ? 1 : 0;
            const int kd_hi = (w == 3) ? 2 : 3;
            for (int kd = kd_lo; kd < kd_hi; ++kd) {
                const int tin  = w + kd - 1;
                const int rowt = tin * YT * 34;
                #pragma unroll
                for (int jj = 0; jj < 9; ++jj) {
                    const int ky = jj / 3, kx = jj % 3;     // compile-time
                    short8 a[MT], bf[2 * NR];
                    #pragma unroll
                    for (int mt = 0; mt < MT; ++mt)
                        a[mt] = *(const short8*)
                            &Ag[(size_t)((kd * 9 + jj) * 64 + ocb + mt * 16 + xn) * KCH + kc * 32 + quad * 8];
                    #pragma unroll
                    for (int nt = 0; nt < 2 * NR; ++nt) {
                        const int ysub = nt >> 1, xh = nt & 1;
                        const int row = rowt + (ysub + ky) * 34 + xh * 16 + xn + kx;
                        bf[nt] = *(const short8*)&xs[swz32(row, quad)];
                    }
                    #pragma unroll
                    for (int nt = 0; nt < 2 * NR; ++nt)
                        #pragma unroll
                        for (int mt = 0; mt < MT; ++mt)
                            acc[mt][nt] = __builtin_amdgcn_mfma_f32_16x16x32_bf16(a[mt], bf[nt], acc[mt][nt], 0, 0, 0);
                }
            }
        } else {
            // single center tap (kd=ky=kx=1)
            short8 a[MT], bf[2 * NR];
            #pragma unroll
            for (int mt = 0; mt < MT; ++mt)
                a[mt] = *(const short8*)&Ag[(size_t)(mt * 16 + xn) * KCH + kc * 32 + quad * 8];
            #pragma unroll
            for (int nt = 0; nt < 2 * NR; ++nt) {
                const int ysub = nt >> 1, xh = nt & 1;
                const int row = (w * YT + ysub + 1) * 34 + xh * 16 + xn + 1;
                bf[nt] = *(const short8*)&xs[swz32(row, quad)];
            }
            #pragma unroll
            for (int nt = 0; nt < 2 * NR; ++nt)
                #pragma unroll
                for (int mt = 0; mt < MT; ++mt)
                    acc[mt][nt] = __builtin_amdgcn_mfma_f32_16x16x32_bf16(a[mt], bf[nt], acc[mt][nt], 0, 0, 0);
        }
    }

    // epilogue: C/D layout col=lane&15, row=quad*4+reg
    #pragma unroll
    for (int mt = 0; mt < MT; ++mt)
    #pragma unroll
    for (int nt = 0; nt < 2 * NR; ++nt) {
        const int ysub = nt >> 1, xh = nt & 1;
        const int sp = w * 1024 + (y0 + ysub) * 32 + xh * 16 + xn;
        #pragma unroll
        for (int reg = 0; reg < 4; ++reg) {
            const int oc = ocb + mt * 16 + quad * 4 + reg;
            float bias;
            if (MODE == 0)      bias = bxp[g * 64 + oc] + bhp[g * 64 + oc];
            else if (MODE == 1) bias = bhp[7 * 64 + oc] + bhp[8 * 64 + oc];
            else                bias = b111[oc];
            float* p = outp + (size_t)oc * SP + sp;
            float vv = acc[mt][nt][reg] + bias;
            if (MODE == 1) vv += *p;     // accumulate onto MODE-0 g6 output; each
            *p = vv;                     // element owned by exactly one block
        }
    }
}

// ---- LN3 stats only (gates 0..5): mu/rstd per (g,b,c) -> lnstats table ----
// Activation+normalization is applied on-the-fly by consumers (scores_k, cm_pcm_k),
// eliding the 48 MB activated-gate write pass.
__global__ __launch_bounds__(256) void ln3_stats_k(float* __restrict__ out,
                                                   float* __restrict__ ws,
                                                   float* __restrict__ lnstats)
{
    const int blk = blockIdx.x;                 // g*512 + b*64 + chn
    const int g = blk >> 9;
    const float* p = gate_ptr(out, ws, g) + (size_t)(blk & 511) * SP;
    const int tid = threadIdx.x;

    float s = 0.f, s2 = 0.f;
    for (int k = tid; k < SP; k += 256) { float v = p[k]; s += v; s2 += v * v; }
    #pragma unroll
    for (int off = 32; off > 0; off >>= 1) { s += __shfl_down(s, off); s2 += __shfl_down(s2, off); }
    __shared__ float rs[4], rs2[4];
    if ((tid & 63) == 0) { rs[tid >> 6] = s; rs2[tid >> 6] = s2; }
    __syncthreads();
    if (tid == 0) {
        float S  = rs[0] + rs[1] + rs[2] + rs[3];
        float Sq = rs2[0] + rs2[1] + rs2[2] + rs2[3];
        float mu  = S * (1.f / SP);
        float var = Sq * (1.f / SP) - mu * mu;
        lnstats[2 * blk]     = mu;
        lnstats[2 * blk + 1] = rsqrtf(var + EPS);
    }
}

// ---- LayerNorm + activation in place (gate 6 / o-gate only) ----
__global__ __launch_bounds__(256) void ln3_act_k(float* __restrict__ out,
                                                 float* __restrict__ ws, int gate0)
{
    const int blk = blockIdx.x;
    const int g = gate0 + (blk >> 9);
    float* p = gate_ptr(out, ws, g) + (size_t)(blk & 511) * SP;
    const int tid = threadIdx.x;

    float s = 0.f, s2 = 0.f;
    for (int k = tid; k < SP; k += 256) { float v = p[k]; s += v; s2 += v * v; }
    #pragma unroll
    for (int off = 32; off > 0; off >>= 1) { s += __shfl_down(s, off); s2 += __shfl_down(s2, off); }
    __shared__ float rs[4], rs2[4], stat[2];
    if ((tid & 63) == 0) { rs[tid >> 6] = s; rs2[tid >> 6] = s2; }
    __syncthreads();
    if (tid == 0) {
        float S  = rs[0] + rs[1] + rs[2] + rs[3];
        float Sq = rs2[0] + rs2[1] + rs2[2] + rs2[3];
        float mu  = S * (1.f / SP);
        float var = Sq * (1.f / SP) - mu * mu;
        stat[0] = mu; stat[1] = rsqrtf(var + EPS);
    }
    __syncthreads();
    const float mu = stat[0], r = stat[1];
    for (int k = tid; k < SP; k += 256)
        p[k] = fsig((p[k] - mu) * r);           // gate 6 is sigmoid
}

// ---- attention scores: sigma(LN(u0)) applied on the fly; one r-read, 5 dots ----
__global__ __launch_bounds__(256) void scores_k(const float* __restrict__ u0,
                                                const float* __restrict__ chist,
                                                const float* __restrict__ lnstats,
                                                float* __restrict__ stats)
{
    const int blk = blockIdx.x;            // 512 = 8 b * 64 chn (chunk == channel)
    const int b = blk >> 6, chn = blk & 63;
    const float mu = lnstats[2 * (b * 64 + chn)];
    const float rr = lnstats[2 * (b * 64 + chn) + 1];
    const float* rp = u0 + (size_t)b * CHB;
    const int lo = chn * SP;
    float s[TAU] = {};
    for (int k = lo + threadIdx.x; k < lo + SP; k += 256) {
        const float rv = fsig((rp[k] - mu) * rr);
        #pragma unroll
        for (int l = 0; l < TAU; ++l) s[l] += rv * chist[(size_t)(l * BATCH + b) * CHB + k];
    }
    __shared__ float rsh[TAU][4];
    #pragma unroll
    for (int l = 0; l < TAU; ++l) {
        float v = s[l];
        #pragma unroll
        for (int off = 32; off > 0; off >>= 1) v += __shfl_down(v, off);
        if ((threadIdx.x & 63) == 0) rsh[l][threadIdx.x >> 6] = v;
    }
    __syncthreads();
    if (threadIdx.x < TAU) {
        const int l = threadIdx.x;
        atomicAdd(&stats[l * 8 + b],
                  (rsh[l][0] + rsh[l][1] + rsh[l][2] + rsh[l][3]) * (1.f / 64.f));
    }
}

// ---- z = chist[4,b] + sum_l attn[b,l]*chist[l,b]; softmax fused; per-block partials ----
__global__ __launch_bounds__(256) void recall_k(const float* __restrict__ chist,
                                                float* __restrict__ ws,
                                                float* __restrict__ part)
{
    const float* stats = ws + WS_ST_OFF;
    const int blk = blockIdx.x;
    const int b = blk >> 10;
    const int idx = (blk & 1023) * 256 + threadIdx.x;

    // softmax over dim 0 (batch) of scores[l*8+b], per l — 5 threads, broadcast via LDS
    __shared__ float attn[TAU];
    if (threadIdx.x < TAU) {
        const int l = threadIdx.x;
        float mx = -1e30f;
        for (int bb = 0; bb < BATCH; ++bb) mx = fmaxf(mx, stats[l * 8 + bb]);
        float sum = 0.f, e = 0.f;
        for (int bb = 0; bb < BATCH; ++bb) {
            float t = __expf(stats[l * 8 + bb] - mx);
            sum += t;
            if (bb == b) e = t;
        }
        attn[l] = e / sum;
    }
    __syncthreads();
    const float a0 = attn[0], a1 = attn[1], a2 = attn[2], a3 = attn[3], a4 = attn[4];

    const size_t e = (size_t)b * CHB + idx;
    const size_t LB = (size_t)BATCH * CHB;
    float z = chist[4 * LB + e] * (1.f + a4)
            + a0 * chist[0 * LB + e] + a1 * chist[1 * LB + e]
            + a2 * chist[2 * LB + e] + a3 * chist[3 * LB + e];
    ws[WS_Z_OFF + e] = z;

    float s = z, s2 = z * z;
    #pragma unroll
    for (int off = 32; off > 0; off >>= 1) { s += __shfl_down(s, off); s2 += __shfl_down(s2, off); }
    __shared__ float rs[4], rs2[4];
    if ((threadIdx.x & 63) == 0) { rs[threadIdx.x >> 6] = s; rs2[threadIdx.x >> 6] = s2; }
    __syncthreads();
    if (threadIdx.x == 0) {
        part[blk]        = rs[0] + rs[1] + rs[2] + rs[3];
        part[8192 + blk] = rs2[0] + rs2[1] + rs2[2] + rs2[3];
    }
}

// ---- fused: LN4 stats + LN3+act of gates 1..5 on the fly + c,m_new + PCM pack ----
__global__ __launch_bounds__(256) void cm_pcm_k(float* __restrict__ out, float* __restrict__ ws,
                                                const float* __restrict__ m,
                                                const float* __restrict__ lnw,
                                                const float* __restrict__ lnb,
                                                const float* __restrict__ part,
                                                const float* __restrict__ lnstats,
                                                u16* __restrict__ PCM)
{
    __shared__ __align__(16) u16 tl[64][136];   // [sp][128 ch + pad], 16B-aligned rows
    __shared__ float lst[5][64][2];             // LN3 stats for gates 1..5, this batch
    const int bi = blockIdx.x;
    const int b = bi >> 6;
    const int s0 = (bi & 63) << 6;

    // stage LN3 stats (gates 1..5) + re-reduce the 1024 LN4 partials for this batch
    for (int j = threadIdx.x; j < 5 * 64; j += 256) {
        const int gg = j >> 6, chn = j & 63;
        lst[gg][chn][0] = lnstats[2 * ((gg + 1) * 512 + b * 64 + chn)];
        lst[gg][chn][1] = lnstats[2 * ((gg + 1) * 512 + b * 64 + chn) + 1];
    }
    float s = 0.f, s2 = 0.f;
    for (int j = threadIdx.x; j < 1024; j += 256) {
        s  += part[b * 1024 + j];
        s2 += part[8192 + b * 1024 + j];
    }
    #pragma unroll
    for (int off = 32; off > 0; off >>= 1) { s += __shfl_down(s, off); s2 += __shfl_down(s2, off); }
    __shared__ float rs[4], rs2[4], st[2];
    if ((threadIdx.x & 63) == 0) { rs[threadIdx.x >> 6] = s; rs2[threadIdx.x >> 6] = s2; }
    __syncthreads();
    if (threadIdx.x == 0) {
        float S  = rs[0] + rs[1] + rs[2] + rs[3];
        float Sq = rs2[0] + rs2[1] + rs2[2] + rs2[3];
        float mu  = S * (1.f / CHB);
        float var = Sq * (1.f / CHB) - mu * mu;
        st[0] = mu; st[1] = rsqrtf(var + EPS);
    }
    __syncthreads();
    const float mu = st[0], rstd = st[1];

    for (int i = threadIdx.x; i < 1024; i += 256) {       // 64ch x 16 float4
        const int chn = i >> 4;
        const int sp4 = (i & 15) << 2;
        const size_t e = (size_t)b * CHB + (size_t)chn * SP + s0 + sp4;
        const size_t le = (size_t)chn * SP + s0 + sp4;
        float4 z  = *(const float4*)&ws[WS_Z_OFF + e];
        float4 u1 = *(const float4*)&gate_ptr(out, ws, 1)[e];
        float4 u2 = *(const float4*)&gate_ptr(out, ws, 2)[e];
        float4 u3 = *(const float4*)&gate_ptr(out, ws, 3)[e];
        float4 u4 = *(const float4*)&gate_ptr(out, ws, 4)[e];
        float4 u5 = *(const float4*)&gate_ptr(out, ws, 5)[e];
        float4 mm = *(const float4*)&m[e];
        float4 lw = *(const float4*)&lnw[le];
        float4 lb = *(const float4*)&lnb[le];
        const float m1 = lst[0][chn][0], r1 = lst[0][chn][1];
        const float m2 = lst[1][chn][0], r2 = lst[1][chn][1];
        const float m3 = lst[2][chn][0], r3 = lst[2][chn][1];
        const float m4 = lst[3][chn][0], r4 = lst[3][chn][1];
        const float m5 = lst[4][chn][0], r5 = lst[4][chn][1];
        float4 c, mn;
        {
            const float uu1[4] = {u1.x, u1.y, u1.z, u1.w};
            const float uu2[4] = {u2.x, u2.y, u2.z, u2.w};
            const float uu3[4] = {u3.x, u3.y, u3.z, u3.w};
            const float uu4[4] = {u4.x, u4.y, u4.z, u4.w};
            const float uu5[4] = {u5.x, u5.y, u5.z, u5.w};
            const float zz[4]  = {z.x, z.y, z.z, z.w};
            const float mmv[4] = {mm.x, mm.y, mm.z, mm.w};
            const float lwv[4] = {lw.x, lw.y, lw.z, lw.w};
            const float lbv[4] = {lb.x, lb.y, lb.z, lb.w};
            float cv[4], mv[4];
            #pragma unroll
            for (int k = 0; k < 4; ++k) {
                const float gi = fsig ((uu1[k] - m1) * r1);
                const float gg = ftanh((uu2[k] - m2) * r2);
                const float ip = fsig ((uu3[k] - m3) * r3);
                const float gp = ftanh((uu4[k] - m4) * r4);
                const float fp = fsig ((uu5[k] - m5) * r5);
                cv[k] = gi * gg + (zz[k] - mu) * rstd * lwv[k] + lbv[k];
                mv[k] = ip * gp + fp * mmv[k];
                tl[sp4 + k][chn]      = f2b(cv[k]);
                tl[sp4 + k][64 + chn] = f2b(mv[k]);
            }
            c.x = cv[0]; c.y = cv[1]; c.z = cv[2]; c.w = cv[3];
            mn.x = mv[0]; mn.y = mv[1]; mn.z = mv[2]; mn.w = mv[3];
        }
        *(float4*)&out[(size_t)4 * GATE_SZ + e] = c;
        *(float4*)&out[(size_t)5 * GATE_SZ + e] = mn;
    }
    __syncthreads();
    for (int j = threadIdx.x; j < 1024; j += 256) {       // 64 s x 16 ushort8
        const int sidx = j >> 4, c8 = (j & 15) << 3;
        ushort8 v = *(const ushort8*)&tl[sidx][c8];
        *(ushort8*)&PCM[((size_t)b * 4096 + s0 + sidx) * 128 + c8] = v;
    }
}

// ---- merged tail: c_history_new[0:4] = c_history[1:5]  AND  h_new = o * tanh(v) ----
__global__ __launch_bounds__(256) void tail_k(const float* __restrict__ chist,
                                              const float* __restrict__ o,
                                              const float* __restrict__ v,
                                              float* __restrict__ out)
{
    const int bi = blockIdx.x;
    if (bi < 8192) {
        const size_t i = (size_t)bi * 256 + threadIdx.x;
        ((float4*)out)[i] = ((const float4*)(chist + GATE_SZ))[i];
    } else {
        const size_t i = (size_t)(bi - 8192) * 256 + threadIdx.x;
        float4 ov = ((const float4*)o)[i], vv = ((const float4*)v)[i];
        float4 r;
        r.x = ov.x * ftanh(vv.x); r.y = ov.y * ftanh(vv.y);
        r.z = ov.z * ftanh(vv.z); r.w = ov.w * ftanh(vv.w);
        ((float4*)(out + (size_t)6 * GATE_SZ))[i] = r;
    }
}

extern "C" void kernel_launch(void* const* d_in, const int* in_sizes, int n_in,
                              void* d_out, int out_size, void* d_ws, size_t ws_size,
                              hipStream_t stream)
{
    const float* x    = (const float*)d_in[0];
    const float* ch   = (const float*)d_in[1];
    const float* m    = (const float*)d_in[2];
    const float* h    = (const float*)d_in[3];
    const float* Wx   = (const float*)d_in[4];
    const float* bx   = (const float*)d_in[5];
    const float* Wh   = (const float*)d_in[6];
    const float* bh   = (const float*)d_in[7];
    const float* w111 = (const float*)d_in[8];
    const float* b111 = (const float*)d_in[9];
    const float* lnw  = (const float*)d_in[10];
    const float* lnb  = (const float*)d_in[11];
    float* out = (float*)d_out;
    float* ws  = (float*)d_ws;

    // Scratch placement in DEAD d_out slots (ws stays within the proven
    // 4*GATE_SZ+128-float footprint):
    //   slot 0: u0 (raw r) until scores_k; then PCM (8 MB) written by cm_pcm_k,
    //           read by conv MODE 1/2, finally overwritten by tail_k (hist copy).
    //   slot 4: XH (6 MB) dead after MODE 0; slot rewritten by cm_pcm_k with c.
    //   slot 5: A7 (2.2 MB) dead after MODE 0; rewritten by cm_pcm_k (m_new).
    //   slot 6: XM (6 MB) + Ao/A111 (0.46 MB) + LN4 partials (64 KB) + LN3 stats
    //           (24 KB) — all dead before tail_k writes h_new at the very end.
    u16* XH   = (u16*)(out + (size_t)4 * GATE_SZ);
    u16* A7   = (u16*)(out + (size_t)5 * GATE_SZ);
    u16* XM   = (u16*)(out + (size_t)6 * GATE_SZ);
    u16* Ao   = XM + (size_t)BATCH * 4096 * 96;      // behind XM, same slot
    u16* A111 = Ao + (size_t)NO;
    u16* PCM  = (u16*)out;                           // slot 0 (dead after scores_k)
    float* part    = (float*)(A111 + N1);            // 16384 floats, slot-6 dead zone
    float* lnstats = part + 16384;                   // 6144 floats, slot-6 dead zone
    float* stats   = ws + WS_ST_OFF;

    pack_w_k<<<(N7 + NO + N1 + 255) / 256, 256, 0, stream>>>(Wx, Wh, w111, A7, Ao, A111, stats);
    pack_xhm_k<<<512, 256, 0, stream>>>(x, h, m, XH, XM);

    // MODE 0: oc-split (MT=2), 4 blocks/CU, grid 1792
    conv_mfma_k<96, 27, 2, 0, 2, 4><<<1792, 256, 0, stream>>>(XH, XM, A7, bx, bh, nullptr, out, ws);
    ln3_stats_k<<<3072, 256, 0, stream>>>(out, ws, lnstats);         // gates 0..5 stats only

    scores_k<<<512, 256, 0, stream>>>(out, ch, lnstats, stats);      // sigma(LN(u0)) inline
    recall_k<<<8192, 256, 0, stream>>>(ch, ws, part);                // softmax fused
    cm_pcm_k<<<512, 256, 0, stream>>>(out, ws, m, lnw, lnb, part, lnstats, PCM);

    conv_mfma_k<128, 27, 1, 1, 4, 3><<<256, 256, 0, stream>>>(PCM, nullptr, Ao, nullptr, bh, nullptr, out, ws);
    ln3_act_k<<<512, 256, 0, stream>>>(out, ws, 6);                  // gate 6 (o)
    conv_mfma_k<128, 1, 1, 2, 4, 3><<<256, 256, 0, stream>>>(PCM, nullptr, A111, nullptr, nullptr, b111, out, ws);

    tail_k<<<10240, 256, 0, stream>>>(ch, ws + (size_t)2 * GATE_SZ, ws, out);
}